// Round 8
// baseline (232.918 us; speedup 1.0000x reference)
//
#include <hip/hip_runtime.h>
#include <type_traits>

#define NN 50000
#define NE 600000
#define FEAT 128
#define HID 256

typedef float v4f __attribute__((ext_vector_type(4)));
typedef float f32x4 __attribute__((ext_vector_type(4)));
typedef __bf16 bf16x8 __attribute__((ext_vector_type(8)));
using u16 = unsigned short;
using u32 = unsigned int;
typedef u16 u16x4 __attribute__((ext_vector_type(4)));
typedef u16 u16x8 __attribute__((ext_vector_type(8)));

__device__ __forceinline__ u16 f2bf(float f) {
    u32 u = __builtin_bit_cast(u32, f);
    u += 0x7fffu + ((u >> 16) & 1u);   // RNE
    return (u16)(u >> 16);
}
__device__ __forceinline__ float bf2f(u16 h) {
    u32 u = ((u32)h) << 16;
    return __builtin_bit_cast(float, u);
}

// ---------------- CSR build ----------------
__global__ void count_deg_k(const int* __restrict__ dst, int* __restrict__ cnt) {
    int e = blockIdx.x * 256 + threadIdx.x;
    if (e < NE) atomicAdd(&cnt[dst[e]], 1);
}

__global__ __launch_bounds__(256) void scan1_k(const int* __restrict__ cnt,
                                               int* __restrict__ local,
                                               int* __restrict__ bsum) {
    __shared__ int lds[256];
    int t = threadIdx.x;
    int i = blockIdx.x * 256 + t;
    int v = (i < NN) ? cnt[i] : 0;
    lds[t] = v;
    __syncthreads();
    #pragma unroll
    for (int d = 1; d < 256; d <<= 1) {
        int u = (t >= d) ? lds[t - d] : 0;
        __syncthreads();
        lds[t] += u;
        __syncthreads();
    }
    if (i < NN) local[i] = lds[t] - v;
    if (t == 255) bsum[blockIdx.x] = lds[255];
}

// merged scan2+scan3: every block redundantly scans the 196 block sums in LDS
__global__ __launch_bounds__(256) void scan_apply_k(const int* __restrict__ local,
                                                    const int* __restrict__ bsum,
                                                    int* __restrict__ rowptr,
                                                    int* __restrict__ cursor, int nblk) {
    __shared__ int lds[256];
    int t = threadIdx.x;
    int v = (t < nblk) ? bsum[t] : 0;
    lds[t] = v;
    __syncthreads();
    #pragma unroll
    for (int d = 1; d < 256; d <<= 1) {
        int u = (t >= d) ? lds[t - d] : 0;
        __syncthreads();
        lds[t] += u;
        __syncthreads();
    }
    int boff = lds[blockIdx.x] - bsum[blockIdx.x];
    int i = blockIdx.x * 256 + t;
    if (i < NN) {
        int r = local[i] + boff;
        rowptr[i] = r;
        cursor[i] = r;
    }
    if (blockIdx.x == 0 && t == 0) rowptr[NN] = NE;
}

__global__ void fill_k(const int* __restrict__ src, const int* __restrict__ dst,
                       int* __restrict__ cursor, int* __restrict__ col) {
    int e = blockIdx.x * 256 + threadIdx.x;
    if (e < NE) {
        int p = atomicAdd(&cursor[dst[e]], 1);
        col[p] = src[e];
    }
}

// ---------------- combined prep: cvt feats, transpose+cvt W1/W2/Wd1 ----------------
#define NB_CVT 6250           // NN*FEAT/4/256
#define NB_W1  128
#define NB_W2  256
#define NB_WD1 256
__global__ __launch_bounds__(256) void prep_k(const float* __restrict__ feats,
                                              const float* __restrict__ W1,
                                              const float* __restrict__ W2,
                                              const float* __restrict__ Wd1,
                                              u16* __restrict__ featsbf,
                                              u16* __restrict__ WT1,
                                              u16* __restrict__ WT2,
                                              u16* __restrict__ WTd1) {
    int b = blockIdx.x, t = threadIdx.x;
    if (b < NB_CVT) {
        int i = b * 256 + t;
        v4f v = *(const v4f*)(feats + (size_t)i * 4);
        u16x4 o;
        #pragma unroll
        for (int j = 0; j < 4; j++) o[j] = f2bf(v[j]);
        *(u16x4*)(featsbf + (size_t)i * 4) = o;
    } else if (b < NB_CVT + NB_W1) {
        int idx = (b - NB_CVT) * 256 + t;
        int k = idx >> 8, n = idx & 255;
        WT1[(size_t)n * 128 + k] = f2bf(W1[idx]);
    } else if (b < NB_CVT + NB_W1 + NB_W2) {
        int idx = (b - NB_CVT - NB_W1) * 256 + t;
        int k = idx >> 8, n = idx & 255;
        WT2[(size_t)n * 256 + k] = f2bf(W2[idx]);
    } else {
        int idx = (b - NB_CVT - NB_W1 - NB_W2) * 256 + t;
        int k = idx >> 8, n = idx & 255;
        WTd1[(size_t)n * 256 + k] = f2bf(Wd1[idx]);
    }
}

// ------- agg1: grouped 16B/lane gathers, G edges parallel; bf16 out (unchanged) -------
template <int D>
__global__ __launch_bounds__(256) void aggregate_bf_k(const u16* __restrict__ x,
                                                      const int* __restrict__ rowptr,
                                                      const int* __restrict__ col,
                                                      u16* __restrict__ o) {
    constexpr int LPG = (D == 256) ? 32 : 16;
    constexpr int G = 64 / LPG;
    int wave = threadIdx.x >> 6;
    int lane = threadIdx.x & 63;
    int v = blockIdx.x * 4 + wave;
    if (v >= NN) return;
    int g  = lane / LPG;
    int li = lane & (LPG - 1);
    size_t coff = (size_t)li * 8;
    int beg = rowptr[v];
    int deg = rowptr[v + 1] - beg;
    int cnt = deg + 1;
    float acc[8];
    #pragma unroll
    for (int i = 0; i < 8; i++) acc[i] = 0.f;
    int base = 0;
    #pragma unroll 4
    for (; base + G <= cnt; base += G) {
        int idx = base + g;
        int row = (idx < deg) ? col[beg + idx] : v;
        u16x8 r = *(const u16x8*)(x + (size_t)row * D + coff);
        #pragma unroll
        for (int i = 0; i < 8; i++) acc[i] += bf2f(r[i]);
    }
    if (base + g < cnt) {
        int idx = base + g;
        int row = (idx < deg) ? col[beg + idx] : v;
        u16x8 r = *(const u16x8*)(x + (size_t)row * D + coff);
        #pragma unroll
        for (int i = 0; i < 8; i++) acc[i] += bf2f(r[i]);
    }
    #pragma unroll
    for (int i = 0; i < 8; i++) {
        acc[i] += __shfl_xor(acc[i], 32, 64);
        if (G == 4) acc[i] += __shfl_xor(acc[i], 16, 64);
    }
    if (lane < LPG) {
        float inv = 1.0f / (float)cnt;
        u16x8 O;
        #pragma unroll
        for (int i = 0; i < 8; i++) O[i] = f2bf(acc[i] * inv);
        *(u16x8*)(o + (size_t)v * D + coff) = O;
    }
}

#define MFMA_BF16 __builtin_amdgcn_mfma_f32_16x16x32_bf16

// ------- FUSED agg2 + decoder: out[v] = relu(agg(Y2)[v] @ Wd1 + bd1) . wd2 + bd2 -------
// Block = 512 thr / 8 waves, 16 nodes. Wave aggregates 2 nodes (interleaved, D=256,
// 32 lanes/row, 2 edges in flight per node). h2 tile -> LDS (bf16) -> M=16 MFMA vs
// Wd1T (L2-resident, reg-direct) -> relu-dot(wd2) -> per-row reduce -> out.
__global__ __launch_bounds__(512) void agg2_dec_k(const u16* __restrict__ x,
                                                  const int* __restrict__ rowptr,
                                                  const int* __restrict__ col,
                                                  const u16* __restrict__ WTd1,
                                                  const float* __restrict__ bd1,
                                                  const float* __restrict__ wd2,
                                                  const float* __restrict__ bd2,
                                                  float* __restrict__ out) {
    __shared__ __attribute__((aligned(16))) u16 sH[16 * 264];  // 8.25 KB
    __shared__ float sP[8][16];

    int tid = threadIdx.x;
    int w = tid >> 6, lane = tid & 63;
    int g = lane >> 5, li = lane & 31;
    int nbase = blockIdx.x * 16;
    int vA = nbase + w * 2, vB = vA + 1;
    size_t coff = (size_t)li * 8;

    // ---- aggregation of two nodes, interleaved ----
    int begA = rowptr[vA]; int degA = rowptr[vA + 1] - begA; int cntA = degA + 1;
    int begB = rowptr[vB]; int degB = rowptr[vB + 1] - begB; int cntB = degB + 1;
    float aA[8], aB[8];
    #pragma unroll
    for (int i = 0; i < 8; i++) { aA[i] = 0.f; aB[i] = 0.f; }

    int common = (cntA < cntB) ? cntA : cntB;
    int base = 0;
    #pragma unroll 2
    for (; base + 2 <= common; base += 2) {
        int idx = base + g;
        int rA_ = (idx < degA) ? col[begA + idx] : vA;
        int rB_ = (idx < degB) ? col[begB + idx] : vB;
        u16x8 ra = *(const u16x8*)(x + (size_t)rA_ * 256 + coff);
        u16x8 rb = *(const u16x8*)(x + (size_t)rB_ * 256 + coff);
        #pragma unroll
        for (int i = 0; i < 8; i++) { aA[i] += bf2f(ra[i]); aB[i] += bf2f(rb[i]); }
    }
    // tail A
    int ba = base;
    for (; ba + 2 <= cntA; ba += 2) {
        int idx = ba + g;
        int r_ = (idx < degA) ? col[begA + idx] : vA;
        u16x8 r = *(const u16x8*)(x + (size_t)r_ * 256 + coff);
        #pragma unroll
        for (int i = 0; i < 8; i++) aA[i] += bf2f(r[i]);
    }
    if (ba + g < cntA) {
        int idx = ba + g;
        int r_ = (idx < degA) ? col[begA + idx] : vA;
        u16x8 r = *(const u16x8*)(x + (size_t)r_ * 256 + coff);
        #pragma unroll
        for (int i = 0; i < 8; i++) aA[i] += bf2f(r[i]);
    }
    // tail B
    int bb = base;
    for (; bb + 2 <= cntB; bb += 2) {
        int idx = bb + g;
        int r_ = (idx < degB) ? col[begB + idx] : vB;
        u16x8 r = *(const u16x8*)(x + (size_t)r_ * 256 + coff);
        #pragma unroll
        for (int i = 0; i < 8; i++) aB[i] += bf2f(r[i]);
    }
    if (bb + g < cntB) {
        int idx = bb + g;
        int r_ = (idx < degB) ? col[begB + idx] : vB;
        u16x8 r = *(const u16x8*)(x + (size_t)r_ * 256 + coff);
        #pragma unroll
        for (int i = 0; i < 8; i++) aB[i] += bf2f(r[i]);
    }
    #pragma unroll
    for (int i = 0; i < 8; i++) {
        aA[i] += __shfl_xor(aA[i], 32, 64);
        aB[i] += __shfl_xor(aB[i], 32, 64);
    }
    if (lane < 32) {
        float invA = 1.0f / (float)cntA, invB = 1.0f / (float)cntB;
        u16x8 OA, OB;
        #pragma unroll
        for (int i = 0; i < 8; i++) { OA[i] = f2bf(aA[i] * invA); OB[i] = f2bf(aB[i] * invB); }
        *(u16x8*)(&sH[(w * 2 + 0) * 264 + li * 8]) = OA;
        *(u16x8*)(&sH[(w * 2 + 1) * 264 + li * 8]) = OB;
    }
    __syncthreads();

    // ---- decoder: 16x256 tile @ Wd1T; wave w owns cols [w*32, w*32+32) ----
    int r16 = lane & 15, sl = lane >> 4;
    f32x4 acc[2];
    acc[0] = (f32x4)0.f; acc[1] = (f32x4)0.f;
    #pragma unroll
    for (int ks = 0; ks < 8; ks++) {
        bf16x8 af = *(const bf16x8*)(&sH[r16 * 264 + ks * 32 + sl * 8]);
        #pragma unroll
        for (int nf = 0; nf < 2; nf++) {
            int n = w * 32 + nf * 16 + r16;
            bf16x8 bfr = *(const bf16x8*)(WTd1 + (size_t)n * 256 + ks * 32 + sl * 8);
            acc[nf] = MFMA_BF16(af, bfr, acc[nf], 0, 0, 0);
        }
    }
    float bd1c[2], wd2c[2];
    #pragma unroll
    for (int nf = 0; nf < 2; nf++) {
        int n = w * 32 + nf * 16 + r16;
        bd1c[nf] = bd1[n];
        wd2c[nf] = wd2[n];
    }
    #pragma unroll
    for (int j = 0; j < 4; j++) {
        float sj = fmaxf(acc[0][j] + bd1c[0], 0.f) * wd2c[0]
                 + fmaxf(acc[1][j] + bd1c[1], 0.f) * wd2c[1];
        sj += __shfl_xor(sj, 1, 64);
        sj += __shfl_xor(sj, 2, 64);
        sj += __shfl_xor(sj, 4, 64);
        sj += __shfl_xor(sj, 8, 64);
        if (r16 == 0) sP[w][sl * 4 + j] = sj;
    }
    __syncthreads();
    if (tid < 16) {
        float s = bd2[0];
        #pragma unroll
        for (int q = 0; q < 8; q++) s += sP[q][tid];
        out[nbase + tid] = s;
    }
}

// ------- FUSED gemm1+gemm2: Y2 = relu(A1 @ W1 + b1) @ W2 + b2 (bf16 out) -------
__global__ __launch_bounds__(512, 4) void fused_gemm12_k(const u16* __restrict__ A1,
                                                         const u16* __restrict__ B1,
                                                         const float* __restrict__ b1,
                                                         const u16* __restrict__ B2,
                                                         const float* __restrict__ b2,
                                                         u16* __restrict__ Y2, int M) {
    __shared__ __attribute__((aligned(16))) u16 sA[2][64 * 32];
    __shared__ __attribute__((aligned(16))) u16 sB[2][256 * 32];
    __shared__ __attribute__((aligned(16))) u16 sH[64 * 264];

    int tid = threadIdx.x;
    int wid = tid >> 6, lane = tid & 63;
    int m0 = blockIdx.x * 64;
    int r16 = lane & 15, sl = lane >> 4, k8 = sl * 8;

    u32 ao[4], bo[2];
    #pragma unroll
    for (int mf = 0; mf < 4; mf++) {
        int ar = mf * 16 + r16;
        ao[mf] = ar * 32 + ((sl ^ ((ar >> 1) & 3)) * 8);
    }
    #pragma unroll
    for (int nf = 0; nf < 2; nf++) {
        int bc = wid * 32 + nf * 16 + r16;
        bo[nf] = bc * 32 + ((sl ^ ((bc >> 1) & 3)) * 8);
    }

    f32x4 acc[4][2];
    #pragma unroll
    for (int a = 0; a < 4; a++)
        #pragma unroll
        for (int b = 0; b < 2; b++) acc[a][b] = (f32x4)0.f;

    int aRow = tid >> 2, aS = tid & 3;
    u32 aSw = aRow * 32 + ((aS ^ ((aRow >> 1) & 3)) * 8);
    int gAr = m0 + aRow; if (gAr >= M) gAr = M - 1;
    const u16* gA = A1 + (size_t)gAr * 128 + aS * 8;
    int bRow[2], bS[2]; u32 bSw[2];
    #pragma unroll
    for (int j = 0; j < 2; j++) {
        int idx = tid + j * 512;
        bRow[j] = idx >> 2; bS[j] = idx & 3;
        bSw[j] = bRow[j] * 32 + ((bS[j] ^ ((bRow[j] >> 1) & 3)) * 8);
    }

    uint4 rA, rB0, rB1;

    if (tid < 256) rA = *(const uint4*)gA;
    rB0 = *(const uint4*)(B1 + (size_t)bRow[0] * 128 + bS[0] * 8);
    rB1 = *(const uint4*)(B1 + (size_t)bRow[1] * 128 + bS[1] * 8);
    if (tid < 256) *(uint4*)(&sA[0][aSw]) = rA;
    *(uint4*)(&sB[0][bSw[0]]) = rB0;
    *(uint4*)(&sB[0][bSw[1]]) = rB1;
    __syncthreads();

    #pragma unroll
    for (int kb = 0; kb < 4; kb++) {
        int cur = kb & 1;
        if (kb < 3) {
            if (tid < 256) rA = *(const uint4*)(gA + (kb + 1) * 32);
            rB0 = *(const uint4*)(B1 + (size_t)bRow[0] * 128 + (kb + 1) * 32 + bS[0] * 8);
            rB1 = *(const uint4*)(B1 + (size_t)bRow[1] * 128 + (kb + 1) * 32 + bS[1] * 8);
        }
        bf16x8 a0 = *(const bf16x8*)(&sA[cur][ao[0]]);
        bf16x8 a1 = *(const bf16x8*)(&sA[cur][ao[1]]);
        bf16x8 a2 = *(const bf16x8*)(&sA[cur][ao[2]]);
        bf16x8 a3 = *(const bf16x8*)(&sA[cur][ao[3]]);
        bf16x8 h0 = *(const bf16x8*)(&sB[cur][bo[0]]);
        bf16x8 h1 = *(const bf16x8*)(&sB[cur][bo[1]]);
        acc[0][0] = MFMA_BF16(a0, h0, acc[0][0], 0, 0, 0);
        acc[0][1] = MFMA_BF16(a0, h1, acc[0][1], 0, 0, 0);
        acc[1][0] = MFMA_BF16(a1, h0, acc[1][0], 0, 0, 0);
        acc[1][1] = MFMA_BF16(a1, h1, acc[1][1], 0, 0, 0);
        acc[2][0] = MFMA_BF16(a2, h0, acc[2][0], 0, 0, 0);
        acc[2][1] = MFMA_BF16(a2, h1, acc[2][1], 0, 0, 0);
        acc[3][0] = MFMA_BF16(a3, h0, acc[3][0], 0, 0, 0);
        acc[3][1] = MFMA_BF16(a3, h1, acc[3][1], 0, 0, 0);
        if (kb < 3) {
            int nxt = cur ^ 1;
            if (tid < 256) *(uint4*)(&sA[nxt][aSw]) = rA;
            *(uint4*)(&sB[nxt][bSw[0]]) = rB0;
            *(uint4*)(&sB[nxt][bSw[1]]) = rB1;
        }
        __syncthreads();
    }

    rB0 = *(const uint4*)(B2 + (size_t)bRow[0] * 256 + bS[0] * 8);
    rB1 = *(const uint4*)(B2 + (size_t)bRow[1] * 256 + bS[1] * 8);

    {
        float b1c[2];
        #pragma unroll
        for (int nf = 0; nf < 2; nf++) b1c[nf] = b1[wid * 32 + nf * 16 + r16];
        int rbase = sl * 4;
        #pragma unroll
        for (int mf = 0; mf < 4; mf++)
            #pragma unroll
            for (int j = 0; j < 4; j++) {
                int r = mf * 16 + rbase + j;
                #pragma unroll
                for (int nf = 0; nf < 2; nf++) {
                    int c = wid * 32 + nf * 16 + r16;
                    sH[r * 264 + c] = f2bf(fmaxf(acc[mf][nf][j] + b1c[nf], 0.f));
                }
            }
        #pragma unroll
        for (int a = 0; a < 4; a++)
            #pragma unroll
            for (int b = 0; b < 2; b++) acc[a][b] = (f32x4)0.f;
    }
    *(uint4*)(&sB[0][bSw[0]]) = rB0;
    *(uint4*)(&sB[0][bSw[1]]) = rB1;
    __syncthreads();

    #pragma unroll
    for (int kb = 0; kb < 8; kb++) {
        int cur = kb & 1;
        if (kb < 7) {
            rB0 = *(const uint4*)(B2 + (size_t)bRow[0] * 256 + (kb + 1) * 32 + bS[0] * 8);
            rB1 = *(const uint4*)(B2 + (size_t)bRow[1] * 256 + (kb + 1) * 32 + bS[1] * 8);
        }
        bf16x8 a0 = *(const bf16x8*)(sH + (0 * 16 + r16) * 264 + kb * 32 + k8);
        bf16x8 a1 = *(const bf16x8*)(sH + (1 * 16 + r16) * 264 + kb * 32 + k8);
        bf16x8 a2 = *(const bf16x8*)(sH + (2 * 16 + r16) * 264 + kb * 32 + k8);
        bf16x8 a3 = *(const bf16x8*)(sH + (3 * 16 + r16) * 264 + kb * 32 + k8);
        bf16x8 h0 = *(const bf16x8*)(&sB[cur][bo[0]]);
        bf16x8 h1 = *(const bf16x8*)(&sB[cur][bo[1]]);
        acc[0][0] = MFMA_BF16(a0, h0, acc[0][0], 0, 0, 0);
        acc[0][1] = MFMA_BF16(a0, h1, acc[0][1], 0, 0, 0);
        acc[1][0] = MFMA_BF16(a1, h0, acc[1][0], 0, 0, 0);
        acc[1][1] = MFMA_BF16(a1, h1, acc[1][1], 0, 0, 0);
        acc[2][0] = MFMA_BF16(a2, h0, acc[2][0], 0, 0, 0);
        acc[2][1] = MFMA_BF16(a2, h1, acc[2][1], 0, 0, 0);
        acc[3][0] = MFMA_BF16(a3, h0, acc[3][0], 0, 0, 0);
        acc[3][1] = MFMA_BF16(a3, h1, acc[3][1], 0, 0, 0);
        if (kb < 7) {
            int nxt = cur ^ 1;
            *(uint4*)(&sB[nxt][bSw[0]]) = rB0;
            *(uint4*)(&sB[nxt][bSw[1]]) = rB1;
        }
        __syncthreads();
    }

    {
        float b2c[2];
        #pragma unroll
        for (int nf = 0; nf < 2; nf++) b2c[nf] = b2[wid * 32 + nf * 16 + r16];
        int rbase = sl * 4;
        #pragma unroll
        for (int mf = 0; mf < 4; mf++)
            #pragma unroll
            for (int j = 0; j < 4; j++) {
                int gr = m0 + mf * 16 + rbase + j;
                if (gr < M) {
                    #pragma unroll
                    for (int nf = 0; nf < 2; nf++) {
                        int gc = wid * 32 + nf * 16 + r16;
                        Y2[(size_t)gr * 256 + gc] = f2bf(acc[mf][nf][j] + b2c[nf]);
                    }
                }
            }
    }
}

extern "C" void kernel_launch(void* const* d_in, const int* in_sizes, int n_in,
                              void* d_out, int out_size, void* d_ws, size_t ws_size,
                              hipStream_t stream) {
    const float* feats = (const float*)d_in[0];
    const int*   src   = (const int*)d_in[1];
    const int*   dst   = (const int*)d_in[2];
    const float* W1    = (const float*)d_in[3];
    const float* b1    = (const float*)d_in[4];
    const float* W2    = (const float*)d_in[5];
    const float* b2    = (const float*)d_in[6];
    const float* Wd1   = (const float*)d_in[7];
    const float* bd1   = (const float*)d_in[8];
    const float* Wd2   = (const float*)d_in[9];
    const float* bd2   = (const float*)d_in[10];
    float* out = (float*)d_out;

    const int SCAN_BLKS = (NN + 255) / 256;  // 196

    char* base = (char*)d_ws;
    size_t off = 0;
    int* cnt    = (int*)(base + off); off += (size_t)NN * 4;
    int* rowptr = (int*)(base + off); off += (size_t)(NN + 1) * 4;
    int* cursor = (int*)(base + off); off += (size_t)NN * 4;
    int* col    = (int*)(base + off); off += (size_t)NE * 4;
    int* local  = (int*)(base + off); off += (size_t)NN * 4;
    int* bsum   = (int*)(base + off); off += 256 * 4;
    u16* WT1  = (u16*)(base + off); off += (size_t)FEAT * 256 * 2;
    u16* WT2  = (u16*)(base + off); off += (size_t)HID * 256 * 2;
    u16* WTd1 = (u16*)(base + off); off += (size_t)HID * 256 * 2;
    off = (off + 255) & ~(size_t)255;
    u16* featsbf = (u16*)(base + off); off += (size_t)NN * FEAT * 2;  // 12.8 MB
    u16* A1      = (u16*)(base + off); off += (size_t)NN * FEAT * 2;  // agg1 out
    u16* Y2bf    = (u16*)(base + off); off += (size_t)NN * HID * 2;   // fused out

    // --- CSR build ---
    hipMemsetAsync(cnt, 0, (size_t)NN * 4, stream);
    count_deg_k<<<(NE + 255) / 256, 256, 0, stream>>>(dst, cnt);
    scan1_k<<<SCAN_BLKS, 256, 0, stream>>>(cnt, local, bsum);
    scan_apply_k<<<SCAN_BLKS, 256, 0, stream>>>(local, bsum, rowptr, cursor, SCAN_BLKS);
    fill_k<<<(NE + 255) / 256, 256, 0, stream>>>(src, dst, cursor, col);

    // --- combined prep (independent of CSR) ---
    prep_k<<<NB_CVT + NB_W1 + NB_W2 + NB_WD1, 256, 0, stream>>>(
        feats, W1, W2, Wd1, featsbf, WT1, WT2, WTd1);

    // layer 1 aggregate (d=128)
    aggregate_bf_k<FEAT><<<(NN + 3) / 4, 256, 0, stream>>>(featsbf, rowptr, col, A1);

    // fused gemm1+relu+gemm2 (pre-aggregation; agg commutes with matmul+bias)
    fused_gemm12_k<<<(NN + 63) / 64, 512, 0, stream>>>(A1, WT1, b1, WT2, b2, Y2bf, NN);

    // fused layer-2 aggregate + decoder -> out
    agg2_dec_k<<<NN / 16, 512, 0, stream>>>(Y2bf, rowptr, col, WTd1, bd1, Wd2, bd2, out);
}